// Round 3
// baseline (769.810 us; speedup 1.0000x reference)
//
#include <hip/hip_runtime.h>
#include <math.h>

// Problem constants (fixed by the reference)
constexpr int   N   = 50000;
constexpr int   E   = 600000;
constexpr int   FIN = 128;
constexpr int   H   = 64;
constexpr int   C   = 40;
constexpr int   K   = 10;
constexpr float CK  = (1.0f - 0.1f) / 10.0f;  // (1-alpha)/K
constexpr float AL  = 0.1f;                   // alpha

// round-to-nearest-even fp32 -> bf16 (returns low 16 bits)
__device__ __forceinline__ unsigned bf16_rne(float f) {
    unsigned u = __float_as_uint(f);
    return (u + 0x7fffu + ((u >> 16) & 1u)) >> 16;
}
__device__ __forceinline__ float bf16_lo(unsigned d) {   // low 16 bits -> f32
    return __uint_as_float(d << 16);
}
__device__ __forceinline__ float bf16_hi(unsigned d) {   // high 16 bits -> f32
    return __uint_as_float(d & 0xffff0000u);
}

// ---------------------------------------------------------------------------
// y0 = x @ W1   (N x 128) @ (128 x 64)
// Block = 1 wave (64 threads). Lane j holds W1[:,j] in 128 VGPRs; x rows are
// wave-uniform -> scalar loads. 16 nodes per wave -> 3125 blocks (~12 w/CU).
// Writes y0 fp32 (for epilogue) and y0 bf16 (hop-0 gather input).
// ---------------------------------------------------------------------------
constexpr int NPW = 16;
__global__ __launch_bounds__(64, 3) void k_gemm1(const float* __restrict__ x,
                                                 const float* __restrict__ W1,
                                                 float* __restrict__ y0,
                                                 unsigned short* __restrict__ y0b) {
    int lane = threadIdx.x;          // output column
    float w[FIN];
#pragma unroll
    for (int k = 0; k < FIN; ++k) w[k] = W1[k * H + lane];
    int node0 = blockIdx.x * NPW;
    for (int n = 0; n < NPW; ++n) {
        int node = node0 + n;
        if (node >= N) break;
        const float* xr = x + (size_t)node * FIN;   // wave-uniform -> s_load
        float s = 0.0f;
#pragma unroll
        for (int k = 0; k < FIN; ++k) s = fmaf(xr[k], w[k], s);
        y0[node * H + lane]  = s;
        y0b[node * H + lane] = (unsigned short)bf16_rne(s);
    }
}

// ---------------------------------------------------------------------------
// Degree (weighted) + per-row edge count via atomics
// ---------------------------------------------------------------------------
__global__ void k_degcount(const int* __restrict__ row, const float* __restrict__ w,
                           float* __restrict__ deg, int* __restrict__ cnt) {
    int e = blockIdx.x * blockDim.x + threadIdx.x;
    if (e >= E) return;
    int r = row[e];
    atomicAdd(&deg[r], w[e]);
    atomicAdd(&cnt[r], 1);
}

__global__ void k_dinv(const float* __restrict__ deg, float* __restrict__ dinv,
                       float* __restrict__ dinv2) {
    int i = blockIdx.x * blockDim.x + threadIdx.x;
    if (i >= N) return;
    float d  = deg[i] + 1.0f;   // + self-loop weight
    float di = rsqrtf(d);
    dinv[i]  = di;
    dinv2[i] = di * di;
}

// ---------------------------------------------------------------------------
// Two-level exclusive scan of cnt[] -> row_ptr[]
// ---------------------------------------------------------------------------
__global__ __launch_bounds__(1024) void k_scan_blocks(const int* __restrict__ cnt,
                                                      int* __restrict__ row_ptr,
                                                      int* __restrict__ bsum) {
    __shared__ int s[1024];
    int gid = blockIdx.x * 1024 + threadIdx.x;
    int v = (gid < N) ? cnt[gid] : 0;
    s[threadIdx.x] = v;
    __syncthreads();
    for (int off = 1; off < 1024; off <<= 1) {
        int t = (threadIdx.x >= off) ? s[threadIdx.x - off] : 0;
        __syncthreads();
        s[threadIdx.x] += t;
        __syncthreads();
    }
    if (gid < N) row_ptr[gid] = s[threadIdx.x] - v;  // exclusive
    if (threadIdx.x == 1023) bsum[blockIdx.x] = s[1023];
}

__global__ void k_scan_sums(const int* __restrict__ bsum, int* __restrict__ boff, int nb) {
    int lane = threadIdx.x;  // single 64-lane wave
    int orig = (lane < nb) ? bsum[lane] : 0;
    int v = orig;
    for (int off = 1; off < 64; off <<= 1) {
        int t = __shfl_up(v, off, 64);
        if (lane >= off) v += t;
    }
    if (lane < nb) boff[lane] = v - orig;  // exclusive
}

__global__ __launch_bounds__(1024) void k_addoff(int* __restrict__ row_ptr,
                                                 const int* __restrict__ boff) {
    int gid = blockIdx.x * 1024 + threadIdx.x;
    if (gid < N) row_ptr[gid] += boff[blockIdx.x];
    if (gid == 0) row_ptr[N] = E;
}

// ---------------------------------------------------------------------------
// Scatter edges into CSR; packed (col, normalized weight) per edge (8 B)
// ---------------------------------------------------------------------------
__global__ void k_scatter(const int* __restrict__ row, const int* __restrict__ col,
                          const float* __restrict__ w, const float* __restrict__ dinv,
                          const int* __restrict__ row_ptr, int* __restrict__ fill,
                          int2* __restrict__ ep) {
    int e = blockIdx.x * blockDim.x + threadIdx.x;
    if (e >= E) return;
    int r = row[e], c = col[e];
    int p = row_ptr[r] + atomicAdd(&fill[r], 1);
    ep[p] = make_int2(c, __float_as_int(dinv[r] * w[e] * dinv[c]));
}

// ---------------------------------------------------------------------------
// One propagation hop, bf16 h storage, 8-edge-parallel gather:
//   wave = 1 node; 8 subgroups of 8 lanes; subgroup g handles edge j+g; lane
//   covers 8 features via one uint4 (16 B = 8 bf16). One dwordx4 gathers 8
//   edges. 3 shfl_down rounds reduce; lanes 0-7 add self term and write.
//   acc stays fp32.
// ---------------------------------------------------------------------------
template <bool WRITE_H, bool ACC_INIT>
__global__ __launch_bounds__(256) void k_prop(const uint4* __restrict__ hin,   // N x (H/8) uint4
                                              uint4* __restrict__ hout,
                                              float4* __restrict__ acc4,
                                              const float* __restrict__ dinv2,
                                              const int* __restrict__ row_ptr,
                                              const int2* __restrict__ ep) {
    int node = blockIdx.x * 4 + (threadIdx.x >> 6);
    if (node >= N) return;                 // wave-uniform
    int lane = threadIdx.x & 63;
    int g = lane >> 3;                     // edge slot 0..7
    int l = lane & 7;                      // feature octet (features 8l..8l+7)
    int start = row_ptr[node], end = row_ptr[node + 1];
    float s0 = 0.f, s1 = 0.f, s2 = 0.f, s3 = 0.f, s4 = 0.f, s5 = 0.f, s6 = 0.f, s7 = 0.f;
    for (int j = start; j < end; j += 8) {
        int je = j + g;
        int jc = (je < end) ? je : start;  // loop entered => start valid
        int2  e = ep[jc];
        float w = (je < end) ? __int_as_float(e.y) : 0.0f;
        uint4 v = hin[(size_t)e.x * (H / 8) + l];
        s0 = fmaf(w, bf16_lo(v.x), s0);
        s1 = fmaf(w, bf16_hi(v.x), s1);
        s2 = fmaf(w, bf16_lo(v.y), s2);
        s3 = fmaf(w, bf16_hi(v.y), s3);
        s4 = fmaf(w, bf16_lo(v.z), s4);
        s5 = fmaf(w, bf16_hi(v.z), s5);
        s6 = fmaf(w, bf16_lo(v.w), s6);
        s7 = fmaf(w, bf16_hi(v.w), s7);
    }
    // reduce subgroups: lanes l, l+8, ..., l+56 -> lane l
#pragma unroll
    for (int off = 32; off >= 8; off >>= 1) {
        s0 += __shfl_down(s0, off, 64);
        s1 += __shfl_down(s1, off, 64);
        s2 += __shfl_down(s2, off, 64);
        s3 += __shfl_down(s3, off, 64);
        s4 += __shfl_down(s4, off, 64);
        s5 += __shfl_down(s5, off, 64);
        s6 += __shfl_down(s6, off, 64);
        s7 += __shfl_down(s7, off, 64);
    }
    if (lane < 8) {
        int   base = node * (H / 8) + l;
        float d2 = dinv2[node];
        uint4 hv = hin[base];              // self-loop term
        s0 = fmaf(d2, bf16_lo(hv.x), s0);
        s1 = fmaf(d2, bf16_hi(hv.x), s1);
        s2 = fmaf(d2, bf16_lo(hv.y), s2);
        s3 = fmaf(d2, bf16_hi(hv.y), s3);
        s4 = fmaf(d2, bf16_lo(hv.z), s4);
        s5 = fmaf(d2, bf16_hi(hv.z), s5);
        s6 = fmaf(d2, bf16_lo(hv.w), s6);
        s7 = fmaf(d2, bf16_hi(hv.w), s7);
        if (WRITE_H) {
            uint4 o;
            o.x = (bf16_rne(s1) << 16) | bf16_rne(s0);
            o.y = (bf16_rne(s3) << 16) | bf16_rne(s2);
            o.z = (bf16_rne(s5) << 16) | bf16_rne(s4);
            o.w = (bf16_rne(s7) << 16) | bf16_rne(s6);
            hout[base] = o;
        }
        int ai = node * (H / 4) + 2 * l;   // two float4 per octet
        if (ACC_INIT) {
            acc4[ai]     = make_float4(s0, s1, s2, s3);
            acc4[ai + 1] = make_float4(s4, s5, s6, s7);
        } else {
            float4 a = acc4[ai], b = acc4[ai + 1];
            a.x += s0; a.y += s1; a.z += s2; a.w += s3;
            b.x += s4; b.y += s5; b.z += s6; b.w += s7;
            acc4[ai]     = a;
            acc4[ai + 1] = b;
        }
    }
}

// ---------------------------------------------------------------------------
// out = relu(CK*acc + AL*y0 + b1) @ W2 + b2
// ---------------------------------------------------------------------------
__global__ __launch_bounds__(256) void k_final(const float4* __restrict__ y04,
                                               const float4* __restrict__ acc4,
                                               const float* __restrict__ b1,
                                               const float* __restrict__ W2,
                                               const float* __restrict__ b2,
                                               float* __restrict__ out) {
    __shared__ float w2s[H * C];   // 10 KB
    __shared__ float hs[32 * H];   // 8 KB
    __shared__ float b2s[C];
    for (int t = threadIdx.x; t < H * C; t += 256) w2s[t] = W2[t];
    if (threadIdx.x < C) b2s[threadIdx.x] = b2[threadIdx.x];
    int node0 = blockIdx.x * 32;
    for (int t = threadIdx.x; t < 32 * (H / 4); t += 256) {   // 512 float4
        int nl = t >> 4;           // / (H/4)
        int kq = t & 15;           // feature quad
        int node = node0 + nl;
        float4 z = make_float4(0.f, 0.f, 0.f, 0.f);
        if (node < N) {
            int g = node * (H / 4) + kq;
            float4 a = acc4[g], y = y04[g];
            z.x = fmaxf(fmaf(CK, a.x, fmaf(AL, y.x, b1[kq * 4 + 0])), 0.f);
            z.y = fmaxf(fmaf(CK, a.y, fmaf(AL, y.y, b1[kq * 4 + 1])), 0.f);
            z.z = fmaxf(fmaf(CK, a.z, fmaf(AL, y.z, b1[kq * 4 + 2])), 0.f);
            z.w = fmaxf(fmaf(CK, a.w, fmaf(AL, y.w, b1[kq * 4 + 3])), 0.f);
        }
        ((float4*)hs)[t] = z;
    }
    __syncthreads();
    for (int o = threadIdx.x; o < 32 * C; o += 256) {
        int nl = o / C, c = o % C;
        int node = node0 + nl;
        if (node >= N) continue;
        float s = b2s[c];
        const float* hr = &hs[nl * H];
#pragma unroll
        for (int k = 0; k < H; ++k) s = fmaf(hr[k], w2s[k * C + c], s);
        out[node * C + c] = s;
    }
}

// ---------------------------------------------------------------------------
extern "C" void kernel_launch(void* const* d_in, const int* in_sizes, int n_in,
                              void* d_out, int out_size, void* d_ws, size_t ws_size,
                              hipStream_t stream) {
    const float* x  = (const float*)d_in[0];
    const int*   ei = (const int*)d_in[1];
    const float* ew = (const float*)d_in[2];
    const float* W1 = (const float*)d_in[3];
    const float* b1 = (const float*)d_in[4];
    const float* W2 = (const float*)d_in[5];
    const float* b2 = (const float*)d_in[6];
    float* out = (float*)d_out;

    const int* row = ei;        // edge_index[0]
    const int* col = ei + E;    // edge_index[1]

    // bump allocator over workspace (1 KiB aligned)
    char* ws = (char*)d_ws;
    size_t off = 0;
    auto alloc = [&](size_t bytes) -> char* {
        char* p = ws + off;
        off = (off + bytes + 1023) & ~(size_t)1023;
        return p;
    };
    float*          y0  = (float*)alloc((size_t)N * H * 4);
    unsigned short* y0b = (unsigned short*)alloc((size_t)N * H * 2);
    unsigned short* ha  = (unsigned short*)alloc((size_t)N * H * 2);
    unsigned short* hb  = (unsigned short*)alloc((size_t)N * H * 2);
    float* acc    = (float*)alloc((size_t)N * H * 4);
    float* deg    = (float*)alloc((size_t)N * 4);      // zeroed
    int*   cnt    = (int*)  alloc((size_t)N * 4);      // zeroed
    int*   fill   = (int*)  alloc((size_t)N * 4);      // zeroed
    float* dinv   = (float*)alloc((size_t)N * 4);
    float* dinv2  = (float*)alloc((size_t)N * 4);
    int*   row_ptr= (int*)  alloc((size_t)(N + 1) * 4);
    int*   bsum   = (int*)  alloc(64 * 4);
    int*   boff   = (int*)  alloc(64 * 4);
    int2*  ep     = (int2*) alloc((size_t)E * 8);

    // zero the deg|cnt|fill span (contiguous in bump order); acc init'd by hop 0
    hipMemsetAsync(deg, 0, (size_t)((char*)dinv - (char*)deg), stream);

    // 1) y0 = x @ W1 (fp32 out + bf16 out)
    k_gemm1<<<(N + NPW - 1) / NPW, 64, 0, stream>>>(x, W1, y0, y0b);

    // 2) degrees + counts
    k_degcount<<<(E + 255) / 256, 256, 0, stream>>>(row, ew, deg, cnt);
    k_dinv<<<(N + 255) / 256, 256, 0, stream>>>(deg, dinv, dinv2);

    // 3) scan counts -> row_ptr
    constexpr int NB = (N + 1023) / 1024;  // 49
    k_scan_blocks<<<NB, 1024, 0, stream>>>(cnt, row_ptr, bsum);
    k_scan_sums<<<1, 64, 0, stream>>>(bsum, boff, NB);
    k_addoff<<<NB, 1024, 0, stream>>>(row_ptr, boff);

    // 4) CSR scatter with normalized weights (packed col+w)
    k_scatter<<<(E + 255) / 256, 256, 0, stream>>>(row, col, ew, dinv, row_ptr, fill, ep);

    // 5) K propagation hops (ping-pong bf16); hop 0 inits acc, last skips hout
    const uint4* hin = (const uint4*)y0b;
    uint4* bufs[2] = {(uint4*)ha, (uint4*)hb};
    float4* acc4 = (float4*)acc;
    int grid = (N + 3) / 4;
    for (int hop = 0; hop < K; ++hop) {
        uint4* hout = bufs[hop & 1];
        if (hop == 0)
            k_prop<true, true><<<grid, 256, 0, stream>>>(hin, hout, acc4, dinv2, row_ptr, ep);
        else if (hop == K - 1)
            k_prop<false, false><<<grid, 256, 0, stream>>>(hin, hout, acc4, dinv2, row_ptr, ep);
        else
            k_prop<true, false><<<grid, 256, 0, stream>>>(hin, hout, acc4, dinv2, row_ptr, ep);
        hin = hout;
    }

    // 6) fused epilogue MLP
    k_final<<<(N + 31) / 32, 256, 0, stream>>>((const float4*)y0, acc4, b1, W2, b2, out);
}

// Round 4
// 466.270 us; speedup vs baseline: 1.6510x; 1.6510x over previous
//
#include <hip/hip_runtime.h>
#include <math.h>

// Problem constants (fixed by the reference)
constexpr int   N   = 50000;
constexpr int   E   = 600000;
constexpr int   FIN = 128;
constexpr int   H   = 64;
constexpr int   C   = 40;
constexpr int   K   = 10;
constexpr float CK  = (1.0f - 0.1f) / 10.0f;  // (1-alpha)/K
constexpr float AL  = 0.1f;                   // alpha

// round-to-nearest-even fp32 -> bf16 (returns low 16 bits)
__device__ __forceinline__ unsigned bf16_rne(float f) {
    unsigned u = __float_as_uint(f);
    return (u + 0x7fffu + ((u >> 16) & 1u)) >> 16;
}
__device__ __forceinline__ float bf16_lo(unsigned d) {   // low 16 bits -> f32
    return __uint_as_float(d << 16);
}
__device__ __forceinline__ float bf16_hi(unsigned d) {   // high 16 bits -> f32
    return __uint_as_float(d & 0xffff0000u);
}

// ---------------------------------------------------------------------------
// y0 = x @ W1   (N x 128) @ (128 x 64)
// 64 nodes/block, 256 threads. W1 (32KB) + 64 x-rows (pad 132 -> max 2-way
// bank aliasing = free) in LDS. Thread computes a 4x4 node x col tile:
// per k, 1 ds_read_b128 (W1) + 4 ds_read_b32 (x, 16-lane broadcast) -> 16 FMA.
// Writes y0 fp32 (epilogue) and y0 bf16 (hop-0 gather input).
// ---------------------------------------------------------------------------
constexpr int G1N  = 64;    // nodes per block
constexpr int XPAD = 132;   // x-row stride in LDS floats (132*4 % 16 == 0)
__global__ __launch_bounds__(256, 2) void k_gemm1(const float* __restrict__ x,
                                                  const float* __restrict__ W1,
                                                  float* __restrict__ y0,
                                                  unsigned short* __restrict__ y0b) {
    __shared__ float ws[FIN * H];      // 32 KB
    __shared__ float xs[G1N * XPAD];   // 33 KB
    const float4* W14 = (const float4*)W1;
    const float4* x4  = (const float4*)x;
    int t = threadIdx.x;
    int node0 = blockIdx.x * G1N;
    // stage W1 (2048 float4)
    for (int i = t; i < FIN * H / 4; i += 256) ((float4*)ws)[i] = W14[i];
    // stage 64 x rows (2048 float4), coalesced; pad OOB with 0
    for (int p = 0; p < 8; ++p) {
        int idx = p * 256 + t;
        int n   = idx >> 5;            // node-in-block 0..63
        int kk  = idx & 31;            // float4 index in row
        int node = node0 + n;
        float4 v = (node < N) ? x4[(size_t)node * (FIN / 4) + kk]
                              : make_float4(0.f, 0.f, 0.f, 0.f);
        *(float4*)(xs + n * XPAD + kk * 4) = v;
    }
    __syncthreads();
    int ng = t >> 4;                   // node group 0..15
    int cg = t & 15;                   // col group 0..15
    int nb = ng * 4;
    int cb = cg * 4;
    float a00=0,a01=0,a02=0,a03=0, a10=0,a11=0,a12=0,a13=0;
    float a20=0,a21=0,a22=0,a23=0, a30=0,a31=0,a32=0,a33=0;
#pragma unroll 8
    for (int k = 0; k < FIN; ++k) {
        float4 wv = *(const float4*)(ws + k * H + cb);
        float x0 = xs[(nb + 0) * XPAD + k];
        float x1 = xs[(nb + 1) * XPAD + k];
        float x2 = xs[(nb + 2) * XPAD + k];
        float x3 = xs[(nb + 3) * XPAD + k];
        a00 = fmaf(x0, wv.x, a00); a01 = fmaf(x0, wv.y, a01);
        a02 = fmaf(x0, wv.z, a02); a03 = fmaf(x0, wv.w, a03);
        a10 = fmaf(x1, wv.x, a10); a11 = fmaf(x1, wv.y, a11);
        a12 = fmaf(x1, wv.z, a12); a13 = fmaf(x1, wv.w, a13);
        a20 = fmaf(x2, wv.x, a20); a21 = fmaf(x2, wv.y, a21);
        a22 = fmaf(x2, wv.z, a22); a23 = fmaf(x2, wv.w, a23);
        a30 = fmaf(x3, wv.x, a30); a31 = fmaf(x3, wv.y, a31);
        a32 = fmaf(x3, wv.z, a32); a33 = fmaf(x3, wv.w, a33);
    }
    // write 4 nodes x 4 cols
    float4 r0 = make_float4(a00, a01, a02, a03);
    float4 r1 = make_float4(a10, a11, a12, a13);
    float4 r2 = make_float4(a20, a21, a22, a23);
    float4 r3 = make_float4(a30, a31, a32, a33);
    float4 rows[4] = {r0, r1, r2, r3};
#pragma unroll
    for (int i = 0; i < 4; ++i) {
        int node = node0 + nb + i;
        if (node >= N) break;
        float4 r = rows[i];
        *(float4*)(y0 + (size_t)node * H + cb) = r;
        uint2 pb;
        pb.x = (bf16_rne(r.y) << 16) | bf16_rne(r.x);
        pb.y = (bf16_rne(r.w) << 16) | bf16_rne(r.z);
        *(uint2*)(y0b + (size_t)node * H + cb) = pb;
    }
}

// ---------------------------------------------------------------------------
// Degree (weighted) + per-row edge count via atomics
// ---------------------------------------------------------------------------
__global__ void k_degcount(const int* __restrict__ row, const float* __restrict__ w,
                           float* __restrict__ deg, int* __restrict__ cnt) {
    int e = blockIdx.x * blockDim.x + threadIdx.x;
    if (e >= E) return;
    int r = row[e];
    atomicAdd(&deg[r], w[e]);
    atomicAdd(&cnt[r], 1);
}

__global__ void k_dinv(const float* __restrict__ deg, float* __restrict__ dinv,
                       float* __restrict__ dinv2) {
    int i = blockIdx.x * blockDim.x + threadIdx.x;
    if (i >= N) return;
    float d  = deg[i] + 1.0f;   // + self-loop weight
    float di = rsqrtf(d);
    dinv[i]  = di;
    dinv2[i] = di * di;
}

// ---------------------------------------------------------------------------
// Two-level exclusive scan of cnt[] -> row_ptr[]
// ---------------------------------------------------------------------------
__global__ __launch_bounds__(1024) void k_scan_blocks(const int* __restrict__ cnt,
                                                      int* __restrict__ row_ptr,
                                                      int* __restrict__ bsum) {
    __shared__ int s[1024];
    int gid = blockIdx.x * 1024 + threadIdx.x;
    int v = (gid < N) ? cnt[gid] : 0;
    s[threadIdx.x] = v;
    __syncthreads();
    for (int off = 1; off < 1024; off <<= 1) {
        int t = (threadIdx.x >= off) ? s[threadIdx.x - off] : 0;
        __syncthreads();
        s[threadIdx.x] += t;
        __syncthreads();
    }
    if (gid < N) row_ptr[gid] = s[threadIdx.x] - v;  // exclusive
    if (threadIdx.x == 1023) bsum[blockIdx.x] = s[1023];
}

__global__ void k_scan_sums(const int* __restrict__ bsum, int* __restrict__ boff, int nb) {
    int lane = threadIdx.x;  // single 64-lane wave
    int orig = (lane < nb) ? bsum[lane] : 0;
    int v = orig;
    for (int off = 1; off < 64; off <<= 1) {
        int t = __shfl_up(v, off, 64);
        if (lane >= off) v += t;
    }
    if (lane < nb) boff[lane] = v - orig;  // exclusive
}

__global__ __launch_bounds__(1024) void k_addoff(int* __restrict__ row_ptr,
                                                 const int* __restrict__ boff) {
    int gid = blockIdx.x * 1024 + threadIdx.x;
    if (gid < N) row_ptr[gid] += boff[blockIdx.x];
    if (gid == 0) row_ptr[N] = E;
}

// ---------------------------------------------------------------------------
// Scatter edges into CSR; packed (col, normalized weight) per edge (8 B)
// ---------------------------------------------------------------------------
__global__ void k_scatter(const int* __restrict__ row, const int* __restrict__ col,
                          const float* __restrict__ w, const float* __restrict__ dinv,
                          const int* __restrict__ row_ptr, int* __restrict__ fill,
                          int2* __restrict__ ep) {
    int e = blockIdx.x * blockDim.x + threadIdx.x;
    if (e >= E) return;
    int r = row[e], c = col[e];
    int p = row_ptr[r] + atomicAdd(&fill[r], 1);
    ep[p] = make_int2(c, __float_as_int(dinv[r] * w[e] * dinv[c]));
}

// ---------------------------------------------------------------------------
// One propagation hop, bf16 h storage, 8-edge-parallel gather:
//   wave = 1 node; 8 subgroups of 8 lanes; subgroup g handles edge j+g; lane
//   covers 8 features via one uint4 (16 B = 8 bf16). One dwordx4 gathers 8
//   edges. 3 shfl_down rounds reduce; lanes 0-7 add self term and write.
//   acc stays fp32.
// ---------------------------------------------------------------------------
template <bool WRITE_H, bool ACC_INIT>
__global__ __launch_bounds__(256) void k_prop(const uint4* __restrict__ hin,   // N x (H/8) uint4
                                              uint4* __restrict__ hout,
                                              float4* __restrict__ acc4,
                                              const float* __restrict__ dinv2,
                                              const int* __restrict__ row_ptr,
                                              const int2* __restrict__ ep) {
    int node = blockIdx.x * 4 + (threadIdx.x >> 6);
    if (node >= N) return;                 // wave-uniform
    int lane = threadIdx.x & 63;
    int g = lane >> 3;                     // edge slot 0..7
    int l = lane & 7;                      // feature octet (features 8l..8l+7)
    int start = row_ptr[node], end = row_ptr[node + 1];
    float s0 = 0.f, s1 = 0.f, s2 = 0.f, s3 = 0.f, s4 = 0.f, s5 = 0.f, s6 = 0.f, s7 = 0.f;
    for (int j = start; j < end; j += 8) {
        int je = j + g;
        int jc = (je < end) ? je : start;  // loop entered => start valid
        int2  e = ep[jc];
        float w = (je < end) ? __int_as_float(e.y) : 0.0f;
        uint4 v = hin[(size_t)e.x * (H / 8) + l];
        s0 = fmaf(w, bf16_lo(v.x), s0);
        s1 = fmaf(w, bf16_hi(v.x), s1);
        s2 = fmaf(w, bf16_lo(v.y), s2);
        s3 = fmaf(w, bf16_hi(v.y), s3);
        s4 = fmaf(w, bf16_lo(v.z), s4);
        s5 = fmaf(w, bf16_hi(v.z), s5);
        s6 = fmaf(w, bf16_lo(v.w), s6);
        s7 = fmaf(w, bf16_hi(v.w), s7);
    }
    // reduce subgroups: lanes l, l+8, ..., l+56 -> lane l
#pragma unroll
    for (int off = 32; off >= 8; off >>= 1) {
        s0 += __shfl_down(s0, off, 64);
        s1 += __shfl_down(s1, off, 64);
        s2 += __shfl_down(s2, off, 64);
        s3 += __shfl_down(s3, off, 64);
        s4 += __shfl_down(s4, off, 64);
        s5 += __shfl_down(s5, off, 64);
        s6 += __shfl_down(s6, off, 64);
        s7 += __shfl_down(s7, off, 64);
    }
    if (lane < 8) {
        int   base = node * (H / 8) + l;
        float d2 = dinv2[node];
        uint4 hv = hin[base];              // self-loop term
        s0 = fmaf(d2, bf16_lo(hv.x), s0);
        s1 = fmaf(d2, bf16_hi(hv.x), s1);
        s2 = fmaf(d2, bf16_lo(hv.y), s2);
        s3 = fmaf(d2, bf16_hi(hv.y), s3);
        s4 = fmaf(d2, bf16_lo(hv.z), s4);
        s5 = fmaf(d2, bf16_hi(hv.z), s5);
        s6 = fmaf(d2, bf16_lo(hv.w), s6);
        s7 = fmaf(d2, bf16_hi(hv.w), s7);
        if (WRITE_H) {
            uint4 o;
            o.x = (bf16_rne(s1) << 16) | bf16_rne(s0);
            o.y = (bf16_rne(s3) << 16) | bf16_rne(s2);
            o.z = (bf16_rne(s5) << 16) | bf16_rne(s4);
            o.w = (bf16_rne(s7) << 16) | bf16_rne(s6);
            hout[base] = o;
        }
        int ai = node * (H / 4) + 2 * l;   // two float4 per octet
        if (ACC_INIT) {
            acc4[ai]     = make_float4(s0, s1, s2, s3);
            acc4[ai + 1] = make_float4(s4, s5, s6, s7);
        } else {
            float4 a = acc4[ai], b = acc4[ai + 1];
            a.x += s0; a.y += s1; a.z += s2; a.w += s3;
            b.x += s4; b.y += s5; b.z += s6; b.w += s7;
            acc4[ai]     = a;
            acc4[ai + 1] = b;
        }
    }
}

// ---------------------------------------------------------------------------
// out = relu(CK*acc + AL*y0 + b1) @ W2 + b2
// ---------------------------------------------------------------------------
__global__ __launch_bounds__(256) void k_final(const float4* __restrict__ y04,
                                               const float4* __restrict__ acc4,
                                               const float* __restrict__ b1,
                                               const float* __restrict__ W2,
                                               const float* __restrict__ b2,
                                               float* __restrict__ out) {
    __shared__ float w2s[H * C];   // 10 KB
    __shared__ float hs[32 * H];   // 8 KB
    __shared__ float b2s[C];
    for (int t = threadIdx.x; t < H * C; t += 256) w2s[t] = W2[t];
    if (threadIdx.x < C) b2s[threadIdx.x] = b2[threadIdx.x];
    int node0 = blockIdx.x * 32;
    for (int t = threadIdx.x; t < 32 * (H / 4); t += 256) {   // 512 float4
        int nl = t >> 4;           // / (H/4)
        int kq = t & 15;           // feature quad
        int node = node0 + nl;
        float4 z = make_float4(0.f, 0.f, 0.f, 0.f);
        if (node < N) {
            int g = node * (H / 4) + kq;
            float4 a = acc4[g], y = y04[g];
            z.x = fmaxf(fmaf(CK, a.x, fmaf(AL, y.x, b1[kq * 4 + 0])), 0.f);
            z.y = fmaxf(fmaf(CK, a.y, fmaf(AL, y.y, b1[kq * 4 + 1])), 0.f);
            z.z = fmaxf(fmaf(CK, a.z, fmaf(AL, y.z, b1[kq * 4 + 2])), 0.f);
            z.w = fmaxf(fmaf(CK, a.w, fmaf(AL, y.w, b1[kq * 4 + 3])), 0.f);
        }
        ((float4*)hs)[t] = z;
    }
    __syncthreads();
    for (int o = threadIdx.x; o < 32 * C; o += 256) {
        int nl = o / C, c = o % C;
        int node = node0 + nl;
        if (node >= N) continue;
        float s = b2s[c];
        const float* hr = &hs[nl * H];
#pragma unroll
        for (int k = 0; k < H; ++k) s = fmaf(hr[k], w2s[k * C + c], s);
        out[node * C + c] = s;
    }
}

// ---------------------------------------------------------------------------
extern "C" void kernel_launch(void* const* d_in, const int* in_sizes, int n_in,
                              void* d_out, int out_size, void* d_ws, size_t ws_size,
                              hipStream_t stream) {
    const float* x  = (const float*)d_in[0];
    const int*   ei = (const int*)d_in[1];
    const float* ew = (const float*)d_in[2];
    const float* W1 = (const float*)d_in[3];
    const float* b1 = (const float*)d_in[4];
    const float* W2 = (const float*)d_in[5];
    const float* b2 = (const float*)d_in[6];
    float* out = (float*)d_out;

    const int* row = ei;        // edge_index[0]
    const int* col = ei + E;    // edge_index[1]

    // bump allocator over workspace (1 KiB aligned)
    char* ws = (char*)d_ws;
    size_t off = 0;
    auto alloc = [&](size_t bytes) -> char* {
        char* p = ws + off;
        off = (off + bytes + 1023) & ~(size_t)1023;
        return p;
    };
    float*          y0  = (float*)alloc((size_t)N * H * 4);
    unsigned short* y0b = (unsigned short*)alloc((size_t)N * H * 2);
    unsigned short* ha  = (unsigned short*)alloc((size_t)N * H * 2);
    unsigned short* hb  = (unsigned short*)alloc((size_t)N * H * 2);
    float* acc    = (float*)alloc((size_t)N * H * 4);
    float* deg    = (float*)alloc((size_t)N * 4);      // zeroed
    int*   cnt    = (int*)  alloc((size_t)N * 4);      // zeroed
    int*   fill   = (int*)  alloc((size_t)N * 4);      // zeroed
    float* dinv   = (float*)alloc((size_t)N * 4);
    float* dinv2  = (float*)alloc((size_t)N * 4);
    int*   row_ptr= (int*)  alloc((size_t)(N + 1) * 4);
    int*   bsum   = (int*)  alloc(64 * 4);
    int*   boff   = (int*)  alloc(64 * 4);
    int2*  ep     = (int2*) alloc((size_t)E * 8);

    // zero the deg|cnt|fill span (contiguous in bump order); acc init'd by hop 0
    hipMemsetAsync(deg, 0, (size_t)((char*)dinv - (char*)deg), stream);

    // 1) y0 = x @ W1 (fp32 out + bf16 out)
    k_gemm1<<<(N + G1N - 1) / G1N, 256, 0, stream>>>(x, W1, y0, y0b);

    // 2) degrees + counts
    k_degcount<<<(E + 255) / 256, 256, 0, stream>>>(row, ew, deg, cnt);
    k_dinv<<<(N + 255) / 256, 256, 0, stream>>>(deg, dinv, dinv2);

    // 3) scan counts -> row_ptr
    constexpr int NB = (N + 1023) / 1024;  // 49
    k_scan_blocks<<<NB, 1024, 0, stream>>>(cnt, row_ptr, bsum);
    k_scan_sums<<<1, 64, 0, stream>>>(bsum, boff, NB);
    k_addoff<<<NB, 1024, 0, stream>>>(row_ptr, boff);

    // 4) CSR scatter with normalized weights (packed col+w)
    k_scatter<<<(E + 255) / 256, 256, 0, stream>>>(row, col, ew, dinv, row_ptr, fill, ep);

    // 5) K propagation hops (ping-pong bf16); hop 0 inits acc, last skips hout
    const uint4* hin = (const uint4*)y0b;
    uint4* bufs[2] = {(uint4*)ha, (uint4*)hb};
    float4* acc4 = (float4*)acc;
    int grid = (N + 3) / 4;
    for (int hop = 0; hop < K; ++hop) {
        uint4* hout = bufs[hop & 1];
        if (hop == 0)
            k_prop<true, true><<<grid, 256, 0, stream>>>(hin, hout, acc4, dinv2, row_ptr, ep);
        else if (hop == K - 1)
            k_prop<false, false><<<grid, 256, 0, stream>>>(hin, hout, acc4, dinv2, row_ptr, ep);
        else
            k_prop<true, false><<<grid, 256, 0, stream>>>(hin, hout, acc4, dinv2, row_ptr, ep);
        hin = hout;
    }

    // 6) fused epilogue MLP
    k_final<<<(N + 31) / 32, 256, 0, stream>>>((const float4*)y0, acc4, b1, W2, b2, out);
}

// Round 5
// 444.789 us; speedup vs baseline: 1.7307x; 1.0483x over previous
//
#include <hip/hip_runtime.h>
#include <hip/hip_fp16.h>
#include <math.h>

// Problem constants (fixed by the reference)
constexpr int   N   = 50000;
constexpr int   E   = 600000;
constexpr int   FIN = 128;
constexpr int   H   = 64;
constexpr int   C   = 40;
constexpr int   K   = 10;
constexpr float CK  = (1.0f - 0.1f) / 10.0f;  // (1-alpha)/K
constexpr float AL  = 0.1f;                   // alpha

// round-to-nearest-even fp32 -> bf16 (returns low 16 bits)
__device__ __forceinline__ unsigned bf16_rne(float f) {
    unsigned u = __float_as_uint(f);
    return (u + 0x7fffu + ((u >> 16) & 1u)) >> 16;
}
__device__ __forceinline__ float bf16_lo(unsigned d) {   // low 16 bits -> f32
    return __uint_as_float(d << 16);
}
__device__ __forceinline__ float bf16_hi(unsigned d) {   // high 16 bits -> f32
    return __uint_as_float(d & 0xffff0000u);
}

// ---------------------------------------------------------------------------
// y0 = x @ W1   (N x 128) @ (128 x 64)
// 64 nodes/block, 256 threads. W1 (32KB) + 64 x-rows (pad 132 -> max 2-way
// bank aliasing = free) in LDS. Thread computes a 4x4 node x col tile.
// ---------------------------------------------------------------------------
constexpr int G1N  = 64;    // nodes per block
constexpr int XPAD = 132;   // x-row stride in LDS floats (132*4 % 16 == 0)
__global__ __launch_bounds__(256, 2) void k_gemm1(const float* __restrict__ x,
                                                  const float* __restrict__ W1,
                                                  float* __restrict__ y0,
                                                  unsigned short* __restrict__ y0b) {
    __shared__ float ws[FIN * H];      // 32 KB
    __shared__ float xs[G1N * XPAD];   // 33 KB
    const float4* W14 = (const float4*)W1;
    const float4* x4  = (const float4*)x;
    int t = threadIdx.x;
    int node0 = blockIdx.x * G1N;
    for (int i = t; i < FIN * H / 4; i += 256) ((float4*)ws)[i] = W14[i];
    for (int p = 0; p < 8; ++p) {
        int idx = p * 256 + t;
        int n   = idx >> 5;
        int kk  = idx & 31;
        int node = node0 + n;
        float4 v = (node < N) ? x4[(size_t)node * (FIN / 4) + kk]
                              : make_float4(0.f, 0.f, 0.f, 0.f);
        *(float4*)(xs + n * XPAD + kk * 4) = v;
    }
    __syncthreads();
    int ng = t >> 4;
    int cg = t & 15;
    int nb = ng * 4;
    int cb = cg * 4;
    float a00=0,a01=0,a02=0,a03=0, a10=0,a11=0,a12=0,a13=0;
    float a20=0,a21=0,a22=0,a23=0, a30=0,a31=0,a32=0,a33=0;
#pragma unroll 8
    for (int k = 0; k < FIN; ++k) {
        float4 wv = *(const float4*)(ws + k * H + cb);
        float x0 = xs[(nb + 0) * XPAD + k];
        float x1 = xs[(nb + 1) * XPAD + k];
        float x2 = xs[(nb + 2) * XPAD + k];
        float x3 = xs[(nb + 3) * XPAD + k];
        a00 = fmaf(x0, wv.x, a00); a01 = fmaf(x0, wv.y, a01);
        a02 = fmaf(x0, wv.z, a02); a03 = fmaf(x0, wv.w, a03);
        a10 = fmaf(x1, wv.x, a10); a11 = fmaf(x1, wv.y, a11);
        a12 = fmaf(x1, wv.z, a12); a13 = fmaf(x1, wv.w, a13);
        a20 = fmaf(x2, wv.x, a20); a21 = fmaf(x2, wv.y, a21);
        a22 = fmaf(x2, wv.z, a22); a23 = fmaf(x2, wv.w, a23);
        a30 = fmaf(x3, wv.x, a30); a31 = fmaf(x3, wv.y, a31);
        a32 = fmaf(x3, wv.z, a32); a33 = fmaf(x3, wv.w, a33);
    }
    float4 rows[4] = {make_float4(a00,a01,a02,a03), make_float4(a10,a11,a12,a13),
                      make_float4(a20,a21,a22,a23), make_float4(a30,a31,a32,a33)};
#pragma unroll
    for (int i = 0; i < 4; ++i) {
        int node = node0 + nb + i;
        if (node >= N) break;
        float4 r = rows[i];
        *(float4*)(y0 + (size_t)node * H + cb) = r;
        uint2 pb;
        pb.x = (bf16_rne(r.y) << 16) | bf16_rne(r.x);
        pb.y = (bf16_rne(r.w) << 16) | bf16_rne(r.z);
        *(uint2*)(y0b + (size_t)node * H + cb) = pb;
    }
}

// ---------------------------------------------------------------------------
// Per-row edge count (single int atomic per edge)
// ---------------------------------------------------------------------------
__global__ void k_count(const int* __restrict__ row, int* __restrict__ cnt) {
    int e = blockIdx.x * blockDim.x + threadIdx.x;
    if (e >= E) return;
    atomicAdd(&cnt[row[e]], 1);
}

// ---------------------------------------------------------------------------
// Two-level exclusive scan of cnt[] -> row_ptr[]
// ---------------------------------------------------------------------------
__global__ __launch_bounds__(1024) void k_scan_blocks(const int* __restrict__ cnt,
                                                      int* __restrict__ row_ptr,
                                                      int* __restrict__ bsum) {
    __shared__ int s[1024];
    int gid = blockIdx.x * 1024 + threadIdx.x;
    int v = (gid < N) ? cnt[gid] : 0;
    s[threadIdx.x] = v;
    __syncthreads();
    for (int off = 1; off < 1024; off <<= 1) {
        int t = (threadIdx.x >= off) ? s[threadIdx.x - off] : 0;
        __syncthreads();
        s[threadIdx.x] += t;
        __syncthreads();
    }
    if (gid < N) row_ptr[gid] = s[threadIdx.x] - v;  // exclusive
    if (threadIdx.x == 1023) bsum[blockIdx.x] = s[1023];
}

__global__ void k_scan_sums(const int* __restrict__ bsum, int* __restrict__ boff, int nb) {
    int lane = threadIdx.x;  // single 64-lane wave
    int orig = (lane < nb) ? bsum[lane] : 0;
    int v = orig;
    for (int off = 1; off < 64; off <<= 1) {
        int t = __shfl_up(v, off, 64);
        if (lane >= off) v += t;
    }
    if (lane < nb) boff[lane] = v - orig;  // exclusive
}

__global__ __launch_bounds__(1024) void k_addoff(int* __restrict__ row_ptr,
                                                 const int* __restrict__ boff) {
    int gid = blockIdx.x * 1024 + threadIdx.x;
    if (gid < N) row_ptr[gid] += boff[blockIdx.x];
    if (gid == 0) row_ptr[N] = E;
}

// ---------------------------------------------------------------------------
// Scatter edges into CSR; raw (col, weight) per edge (8 B)
// ---------------------------------------------------------------------------
__global__ void k_scatter(const int* __restrict__ row, const int* __restrict__ col,
                          const float* __restrict__ w,
                          const int* __restrict__ row_ptr, int* __restrict__ fill,
                          int2* __restrict__ ep) {
    int e = blockIdx.x * blockDim.x + threadIdx.x;
    if (e >= E) return;
    int r = row[e];
    int p = row_ptr[r] + atomicAdd(&fill[r], 1);
    ep[p] = make_int2(col[e], __float_as_int(w[e]));
}

// ---------------------------------------------------------------------------
// Weighted degree from CSR rows (coalesced-ish, no atomics) + dinv/dinv2
// ---------------------------------------------------------------------------
__global__ void k_deg_dinv(const int2* __restrict__ ep, const int* __restrict__ row_ptr,
                           float* __restrict__ dinv, float* __restrict__ dinv2) {
    int i = blockIdx.x * blockDim.x + threadIdx.x;
    if (i >= N) return;
    float d = 1.0f;   // self-loop weight
    int e0 = row_ptr[i], e1 = row_ptr[i + 1];
    for (int j = e0; j < e1; ++j) d += __int_as_float(ep[j].y);
    float di = rsqrtf(d);
    dinv[i]  = di;
    dinv2[i] = di * di;
}

// ---------------------------------------------------------------------------
// Normalize edge weights in place: w <- dinv[r]*w*dinv[c]
// 8 lanes per row, 32 rows per 256-block.
// ---------------------------------------------------------------------------
__global__ __launch_bounds__(256) void k_norm(int2* __restrict__ ep,
                                              const int* __restrict__ row_ptr,
                                              const float* __restrict__ dinv) {
    int node = blockIdx.x * 32 + (threadIdx.x >> 3);
    if (node >= N) return;
    int l = threadIdx.x & 7;
    float dr = dinv[node];
    int e0 = row_ptr[node], e1 = row_ptr[node + 1];
    for (int j = e0 + l; j < e1; j += 8) {
        int2 v = ep[j];
        ep[j] = make_int2(v.x, __float_as_int(__int_as_float(v.y) * dr * dinv[v.x]));
    }
}

// ---------------------------------------------------------------------------
// One propagation hop, bf16 h storage, 8-edge groups x2 unrolled (16 edges in
// flight). acc kept as packed fp16 (RMW in fp32 domain). Wave = 1 node.
// ---------------------------------------------------------------------------
template <bool WRITE_H, bool ACC_INIT>
__global__ __launch_bounds__(256) void k_prop(const uint4* __restrict__ hin,   // N x (H/8) uint4
                                              uint4* __restrict__ hout,
                                              __half* __restrict__ acch,       // N x H fp16
                                              const float* __restrict__ dinv2,
                                              const int* __restrict__ row_ptr,
                                              const int2* __restrict__ ep) {
    int node = blockIdx.x * 4 + (threadIdx.x >> 6);
    if (node >= N) return;                 // wave-uniform
    int lane = threadIdx.x & 63;
    int g = lane >> 3;                     // edge slot 0..7
    int l = lane & 7;                      // feature octet (features 8l..8l+7)
    int start = row_ptr[node], end = row_ptr[node + 1];
    float s0 = 0.f, s1 = 0.f, s2 = 0.f, s3 = 0.f, s4 = 0.f, s5 = 0.f, s6 = 0.f, s7 = 0.f;
    for (int j = start; j < end; j += 16) {
        {   // group A: edges j+g
            int je = j + g;
            int jc = (je < end) ? je : start;
            int2  e = ep[jc];
            float w = (je < end) ? __int_as_float(e.y) : 0.0f;
            uint4 v = hin[(size_t)e.x * (H / 8) + l];
            s0 = fmaf(w, bf16_lo(v.x), s0);
            s1 = fmaf(w, bf16_hi(v.x), s1);
            s2 = fmaf(w, bf16_lo(v.y), s2);
            s3 = fmaf(w, bf16_hi(v.y), s3);
            s4 = fmaf(w, bf16_lo(v.z), s4);
            s5 = fmaf(w, bf16_hi(v.z), s5);
            s6 = fmaf(w, bf16_lo(v.w), s6);
            s7 = fmaf(w, bf16_hi(v.w), s7);
        }
        if (j + 8 < end) {   // group B: edges j+8+g (wave-uniform guard)
            int je = j + 8 + g;
            int jc = (je < end) ? je : start;
            int2  e = ep[jc];
            float w = (je < end) ? __int_as_float(e.y) : 0.0f;
            uint4 v = hin[(size_t)e.x * (H / 8) + l];
            s0 = fmaf(w, bf16_lo(v.x), s0);
            s1 = fmaf(w, bf16_hi(v.x), s1);
            s2 = fmaf(w, bf16_lo(v.y), s2);
            s3 = fmaf(w, bf16_hi(v.y), s3);
            s4 = fmaf(w, bf16_lo(v.z), s4);
            s5 = fmaf(w, bf16_hi(v.z), s5);
            s6 = fmaf(w, bf16_lo(v.w), s6);
            s7 = fmaf(w, bf16_hi(v.w), s7);
        }
    }
    // reduce subgroups: lanes l, l+8, ..., l+56 -> lane l
#pragma unroll
    for (int off = 32; off >= 8; off >>= 1) {
        s0 += __shfl_down(s0, off, 64);
        s1 += __shfl_down(s1, off, 64);
        s2 += __shfl_down(s2, off, 64);
        s3 += __shfl_down(s3, off, 64);
        s4 += __shfl_down(s4, off, 64);
        s5 += __shfl_down(s5, off, 64);
        s6 += __shfl_down(s6, off, 64);
        s7 += __shfl_down(s7, off, 64);
    }
    if (lane < 8) {
        int   base = node * (H / 8) + l;
        float d2 = dinv2[node];
        uint4 hv = hin[base];              // self-loop term
        s0 = fmaf(d2, bf16_lo(hv.x), s0);
        s1 = fmaf(d2, bf16_hi(hv.x), s1);
        s2 = fmaf(d2, bf16_lo(hv.y), s2);
        s3 = fmaf(d2, bf16_hi(hv.y), s3);
        s4 = fmaf(d2, bf16_lo(hv.z), s4);
        s5 = fmaf(d2, bf16_hi(hv.z), s5);
        s6 = fmaf(d2, bf16_lo(hv.w), s6);
        s7 = fmaf(d2, bf16_hi(hv.w), s7);
        if (WRITE_H) {
            uint4 o;
            o.x = (bf16_rne(s1) << 16) | bf16_rne(s0);
            o.y = (bf16_rne(s3) << 16) | bf16_rne(s2);
            o.z = (bf16_rne(s5) << 16) | bf16_rne(s4);
            o.w = (bf16_rne(s7) << 16) | bf16_rne(s6);
            hout[base] = o;
        }
        // acc fp16: 8 halves = 16 B at acch + node*H + l*8
        uint4* ap = (uint4*)(acch + (size_t)node * H + l * 8);
        if (!ACC_INIT) {
            uint4 old = *ap;
            float2 f;
            f = __half22float2(*(__half2*)&old.x); s0 += f.x; s1 += f.y;
            f = __half22float2(*(__half2*)&old.y); s2 += f.x; s3 += f.y;
            f = __half22float2(*(__half2*)&old.z); s4 += f.x; s5 += f.y;
            f = __half22float2(*(__half2*)&old.w); s6 += f.x; s7 += f.y;
        }
        uint4 nv;
        __half2 h;
        h = __floats2half2_rn(s0, s1); nv.x = *(unsigned*)&h;
        h = __floats2half2_rn(s2, s3); nv.y = *(unsigned*)&h;
        h = __floats2half2_rn(s4, s5); nv.z = *(unsigned*)&h;
        h = __floats2half2_rn(s6, s7); nv.w = *(unsigned*)&h;
        *ap = nv;
    }
}

// ---------------------------------------------------------------------------
// out = relu(CK*acc + AL*y0 + b1) @ W2 + b2   (acc is fp16)
// ---------------------------------------------------------------------------
__global__ __launch_bounds__(256) void k_final(const float4* __restrict__ y04,
                                               const __half* __restrict__ acch,
                                               const float* __restrict__ b1,
                                               const float* __restrict__ W2,
                                               const float* __restrict__ b2,
                                               float* __restrict__ out) {
    __shared__ float w2s[H * C];   // 10 KB
    __shared__ float hs[32 * H];   // 8 KB
    __shared__ float b2s[C];
    for (int t = threadIdx.x; t < H * C; t += 256) w2s[t] = W2[t];
    if (threadIdx.x < C) b2s[threadIdx.x] = b2[threadIdx.x];
    int node0 = blockIdx.x * 32;
    for (int t = threadIdx.x; t < 32 * (H / 4); t += 256) {   // 512 quads
        int nl = t >> 4;           // / (H/4)
        int kq = t & 15;           // feature quad
        int node = node0 + nl;
        float4 z = make_float4(0.f, 0.f, 0.f, 0.f);
        if (node < N) {
            int g = node * (H / 4) + kq;
            float4 y = y04[g];
            uint2 u = *(const uint2*)(acch + (size_t)node * H + kq * 4);
            float2 a01 = __half22float2(*(__half2*)&u.x);
            float2 a23 = __half22float2(*(__half2*)&u.y);
            z.x = fmaxf(fmaf(CK, a01.x, fmaf(AL, y.x, b1[kq * 4 + 0])), 0.f);
            z.y = fmaxf(fmaf(CK, a01.y, fmaf(AL, y.y, b1[kq * 4 + 1])), 0.f);
            z.z = fmaxf(fmaf(CK, a23.x, fmaf(AL, y.z, b1[kq * 4 + 2])), 0.f);
            z.w = fmaxf(fmaf(CK, a23.y, fmaf(AL, y.w, b1[kq * 4 + 3])), 0.f);
        }
        ((float4*)hs)[t] = z;
    }
    __syncthreads();
    for (int o = threadIdx.x; o < 32 * C; o += 256) {
        int nl = o / C, c = o % C;
        int node = node0 + nl;
        if (node >= N) continue;
        float s = b2s[c];
        const float* hr = &hs[nl * H];
#pragma unroll
        for (int k = 0; k < H; ++k) s = fmaf(hr[k], w2s[k * C + c], s);
        out[node * C + c] = s;
    }
}

// ---------------------------------------------------------------------------
extern "C" void kernel_launch(void* const* d_in, const int* in_sizes, int n_in,
                              void* d_out, int out_size, void* d_ws, size_t ws_size,
                              hipStream_t stream) {
    const float* x  = (const float*)d_in[0];
    const int*   ei = (const int*)d_in[1];
    const float* ew = (const float*)d_in[2];
    const float* W1 = (const float*)d_in[3];
    const float* b1 = (const float*)d_in[4];
    const float* W2 = (const float*)d_in[5];
    const float* b2 = (const float*)d_in[6];
    float* out = (float*)d_out;

    const int* row = ei;        // edge_index[0]
    const int* col = ei + E;    // edge_index[1]

    // bump allocator over workspace (1 KiB aligned)
    char* ws = (char*)d_ws;
    size_t off = 0;
    auto alloc = [&](size_t bytes) -> char* {
        char* p = ws + off;
        off = (off + bytes + 1023) & ~(size_t)1023;
        return p;
    };
    float*          y0  = (float*)alloc((size_t)N * H * 4);
    unsigned short* y0b = (unsigned short*)alloc((size_t)N * H * 2);
    unsigned short* ha  = (unsigned short*)alloc((size_t)N * H * 2);
    unsigned short* hb  = (unsigned short*)alloc((size_t)N * H * 2);
    __half*         acch= (__half*)alloc((size_t)N * H * 2);
    int*   cnt    = (int*)  alloc((size_t)N * 4);      // zeroed
    int*   fill   = (int*)  alloc((size_t)N * 4);      // zeroed
    float* dinv   = (float*)alloc((size_t)N * 4);
    float* dinv2  = (float*)alloc((size_t)N * 4);
    int*   row_ptr= (int*)  alloc((size_t)(N + 1) * 4);
    int*   bsum   = (int*)  alloc(64 * 4);
    int*   boff   = (int*)  alloc(64 * 4);
    int2*  ep     = (int2*) alloc((size_t)E * 8);

    // zero cnt|fill (contiguous in bump order)
    hipMemsetAsync(cnt, 0, (size_t)((char*)dinv - (char*)cnt), stream);

    // 1) y0 = x @ W1 (fp32 out + bf16 out)
    k_gemm1<<<(N + G1N - 1) / G1N, 256, 0, stream>>>(x, W1, y0, y0b);

    // 2) per-row edge counts (1 atomic/edge)
    k_count<<<(E + 255) / 256, 256, 0, stream>>>(row, cnt);

    // 3) scan counts -> row_ptr
    constexpr int NB = (N + 1023) / 1024;  // 49
    k_scan_blocks<<<NB, 1024, 0, stream>>>(cnt, row_ptr, bsum);
    k_scan_sums<<<1, 64, 0, stream>>>(bsum, boff, NB);
    k_addoff<<<NB, 1024, 0, stream>>>(row_ptr, boff);

    // 4) CSR scatter (raw col+w), then weighted degree + dinv, then normalize
    k_scatter<<<(E + 255) / 256, 256, 0, stream>>>(row, col, ew, row_ptr, fill, ep);
    k_deg_dinv<<<(N + 255) / 256, 256, 0, stream>>>(ep, row_ptr, dinv, dinv2);
    k_norm<<<(N + 31) / 32, 256, 0, stream>>>(ep, row_ptr, dinv);

    // 5) K propagation hops (ping-pong bf16); hop 0 inits acc, last skips hout
    const uint4* hin = (const uint4*)y0b;
    uint4* bufs[2] = {(uint4*)ha, (uint4*)hb};
    int grid = (N + 3) / 4;
    for (int hop = 0; hop < K; ++hop) {
        uint4* hout = bufs[hop & 1];
        if (hop == 0)
            k_prop<true, true><<<grid, 256, 0, stream>>>(hin, hout, acch, dinv2, row_ptr, ep);
        else if (hop == K - 1)
            k_prop<false, false><<<grid, 256, 0, stream>>>(hin, hout, acch, dinv2, row_ptr, ep);
        else
            k_prop<true, false><<<grid, 256, 0, stream>>>(hin, hout, acch, dinv2, row_ptr, ep);
        hin = hout;
    }

    // 6) fused epilogue MLP
    k_final<<<(N + 31) / 32, 256, 0, stream>>>((const float4*)y0, acch, b1, W2, b2, out);
}

// Round 6
// 349.089 us; speedup vs baseline: 2.2052x; 1.2741x over previous
//
#include <hip/hip_runtime.h>
#include <hip/hip_fp16.h>
#include <math.h>

// Problem constants (fixed by the reference)
constexpr int   N   = 50000;
constexpr int   E   = 600000;
constexpr int   FIN = 128;
constexpr int   H   = 64;
constexpr int   C   = 40;
constexpr int   K   = 10;
constexpr float CK  = (1.0f - 0.1f) / 10.0f;  // (1-alpha)/K
constexpr float AL  = 0.1f;                   // alpha

// round-to-nearest-even fp32 -> bf16 (returns low 16 bits)
__device__ __forceinline__ unsigned bf16_rne(float f) {
    unsigned u = __float_as_uint(f);
    return (u + 0x7fffu + ((u >> 16) & 1u)) >> 16;
}
__device__ __forceinline__ float bf16_lo(unsigned d) { return __uint_as_float(d << 16); }
__device__ __forceinline__ float bf16_hi(unsigned d) { return __uint_as_float(d & 0xffff0000u); }

// ---------------------------------------------------------------------------
// y0 = x @ W1   (N x 128) @ (128 x 64)
// 64 nodes/block, 256 threads; W1 + padded x rows in LDS; 4x4 register tile.
// ---------------------------------------------------------------------------
constexpr int G1N  = 64;
constexpr int XPAD = 132;
__global__ __launch_bounds__(256, 2) void k_gemm1(const float* __restrict__ x,
                                                  const float* __restrict__ W1,
                                                  float* __restrict__ y0,
                                                  unsigned short* __restrict__ y0b) {
    __shared__ float ws[FIN * H];
    __shared__ float xs[G1N * XPAD];
    const float4* W14 = (const float4*)W1;
    const float4* x4  = (const float4*)x;
    int t = threadIdx.x;
    int node0 = blockIdx.x * G1N;
    for (int i = t; i < FIN * H / 4; i += 256) ((float4*)ws)[i] = W14[i];
    for (int p = 0; p < 8; ++p) {
        int idx = p * 256 + t;
        int n   = idx >> 5;
        int kk  = idx & 31;
        int node = node0 + n;
        float4 v = (node < N) ? x4[(size_t)node * (FIN / 4) + kk]
                              : make_float4(0.f, 0.f, 0.f, 0.f);
        *(float4*)(xs + n * XPAD + kk * 4) = v;
    }
    __syncthreads();
    int nb = (t >> 4) * 4;
    int cb = (t & 15) * 4;
    float a00=0,a01=0,a02=0,a03=0, a10=0,a11=0,a12=0,a13=0;
    float a20=0,a21=0,a22=0,a23=0, a30=0,a31=0,a32=0,a33=0;
#pragma unroll 8
    for (int k = 0; k < FIN; ++k) {
        float4 wv = *(const float4*)(ws + k * H + cb);
        float x0 = xs[(nb + 0) * XPAD + k];
        float x1 = xs[(nb + 1) * XPAD + k];
        float x2 = xs[(nb + 2) * XPAD + k];
        float x3 = xs[(nb + 3) * XPAD + k];
        a00 = fmaf(x0, wv.x, a00); a01 = fmaf(x0, wv.y, a01);
        a02 = fmaf(x0, wv.z, a02); a03 = fmaf(x0, wv.w, a03);
        a10 = fmaf(x1, wv.x, a10); a11 = fmaf(x1, wv.y, a11);
        a12 = fmaf(x1, wv.z, a12); a13 = fmaf(x1, wv.w, a13);
        a20 = fmaf(x2, wv.x, a20); a21 = fmaf(x2, wv.y, a21);
        a22 = fmaf(x2, wv.z, a22); a23 = fmaf(x2, wv.w, a23);
        a30 = fmaf(x3, wv.x, a30); a31 = fmaf(x3, wv.y, a31);
        a32 = fmaf(x3, wv.z, a32); a33 = fmaf(x3, wv.w, a33);
    }
    float4 rows[4] = {make_float4(a00,a01,a02,a03), make_float4(a10,a11,a12,a13),
                      make_float4(a20,a21,a22,a23), make_float4(a30,a31,a32,a33)};
#pragma unroll
    for (int i = 0; i < 4; ++i) {
        int node = node0 + nb + i;
        if (node >= N) break;
        float4 r = rows[i];
        *(float4*)(y0 + (size_t)node * H + cb) = r;
        uint2 pb;
        pb.x = (bf16_rne(r.y) << 16) | bf16_rne(r.x);
        pb.y = (bf16_rne(r.w) << 16) | bf16_rne(r.z);
        *(uint2*)(y0b + (size_t)node * H + cb) = pb;
    }
}

// ---------------------------------------------------------------------------
// Per-row edge count, 8-way privatized to kill cross-XCD line ping-pong
// ---------------------------------------------------------------------------
__global__ void k_count(const int* __restrict__ row, int* __restrict__ cnt8) {
    int e = blockIdx.x * blockDim.x + threadIdx.x;
    if (e >= E) return;
    atomicAdd(&cnt8[(size_t)(blockIdx.x & 7) * N + row[e]], 1);
}

// ---------------------------------------------------------------------------
// Two-level exclusive scan of summed cnt8 -> row_ptr[]
// ---------------------------------------------------------------------------
__global__ __launch_bounds__(1024) void k_scan_blocks(const int* __restrict__ cnt8,
                                                      int* __restrict__ row_ptr,
                                                      int* __restrict__ bsum) {
    __shared__ int s[1024];
    int gid = blockIdx.x * 1024 + threadIdx.x;
    int v = 0;
    if (gid < N) {
#pragma unroll
        for (int c = 0; c < 8; ++c) v += cnt8[(size_t)c * N + gid];
    }
    s[threadIdx.x] = v;
    __syncthreads();
    for (int off = 1; off < 1024; off <<= 1) {
        int t = (threadIdx.x >= off) ? s[threadIdx.x - off] : 0;
        __syncthreads();
        s[threadIdx.x] += t;
        __syncthreads();
    }
    if (gid < N) row_ptr[gid] = s[threadIdx.x] - v;  // exclusive
    if (threadIdx.x == 1023) bsum[blockIdx.x] = s[1023];
}

__global__ void k_scan_sums(const int* __restrict__ bsum, int* __restrict__ boff, int nb) {
    int lane = threadIdx.x;
    int orig = (lane < nb) ? bsum[lane] : 0;
    int v = orig;
    for (int off = 1; off < 64; off <<= 1) {
        int t = __shfl_up(v, off, 64);
        if (lane >= off) v += t;
    }
    if (lane < nb) boff[lane] = v - orig;
}

__global__ __launch_bounds__(1024) void k_addoff(int* __restrict__ row_ptr,
                                                 const int* __restrict__ boff) {
    int gid = blockIdx.x * 1024 + threadIdx.x;
    if (gid < N) row_ptr[gid] += boff[blockIdx.x];
    if (gid == 0) row_ptr[N] = E;
}

// ---------------------------------------------------------------------------
// Scatter edges into CSR; raw (col, weight) per edge (8 B)
// ---------------------------------------------------------------------------
__global__ void k_scatter(const int* __restrict__ row, const int* __restrict__ col,
                          const float* __restrict__ w,
                          const int* __restrict__ row_ptr, int* __restrict__ fill,
                          int2* __restrict__ ep) {
    int e = blockIdx.x * blockDim.x + threadIdx.x;
    if (e >= E) return;
    int r = row[e];
    int p = row_ptr[r] + atomicAdd(&fill[r], 1);
    ep[p] = make_int2(col[e], __float_as_int(w[e]));
}

// ---------------------------------------------------------------------------
// Weighted degree from CSR rows + dinv/dinv2
// ---------------------------------------------------------------------------
__global__ void k_deg_dinv(const int2* __restrict__ ep, const int* __restrict__ row_ptr,
                           float* __restrict__ dinv, float* __restrict__ dinv2) {
    int i = blockIdx.x * blockDim.x + threadIdx.x;
    if (i >= N) return;
    float d = 1.0f;   // self-loop weight
    int e0 = row_ptr[i], e1 = row_ptr[i + 1];
    for (int j = e0; j < e1; ++j) d += __int_as_float(ep[j].y);
    float di = rsqrtf(d);
    dinv[i]  = di;
    dinv2[i] = di * di;
}

// ---------------------------------------------------------------------------
// Normalize edge weights in place: w <- dinv[r]*w*dinv[c]
// ---------------------------------------------------------------------------
__global__ __launch_bounds__(256) void k_norm(int2* __restrict__ ep,
                                              const int* __restrict__ row_ptr,
                                              const float* __restrict__ dinv) {
    int node = blockIdx.x * 32 + (threadIdx.x >> 3);
    if (node >= N) return;
    int l = threadIdx.x & 7;
    float dr = dinv[node];
    int e0 = row_ptr[node], e1 = row_ptr[node + 1];
    for (int j = e0 + l; j < e1; j += 8) {
        int2 v = ep[j];
        ep[j] = make_int2(v.x, __float_as_int(__int_as_float(v.y) * dr * dinv[v.x]));
    }
}

// ---------------------------------------------------------------------------
// One propagation hop. 8 nodes per wave (lane = node-sub x feature-octet),
// serial predicated edge loop (2x unrolled), no shfl reduction, all lanes
// active in epilogue. 32 nodes/block. FINAL fuses the MLP epilogue.
// ---------------------------------------------------------------------------
template <bool WRITE_H, bool ACC_INIT, bool FINAL>
__global__ __launch_bounds__(256) void k_prop(const uint4* __restrict__ hin,   // N x (H/8)
                                              uint4* __restrict__ hout,
                                              __half* __restrict__ acch,       // N x H fp16
                                              const float* __restrict__ dinv2,
                                              const int* __restrict__ row_ptr,
                                              const int2* __restrict__ ep,
                                              const float4* __restrict__ y04,
                                              const float* __restrict__ b1,
                                              const float* __restrict__ W2,
                                              const float* __restrict__ b2,
                                              float* __restrict__ out) {
    __shared__ float w2s[H * C];   // 10 KB (used only when FINAL)
    __shared__ float hs[32 * H];   // 8 KB
    __shared__ float b2s[C];
    __shared__ float b1s[H];
    int t = threadIdx.x;
    if (FINAL) {
        for (int i = t; i < H * C; i += 256) w2s[i] = W2[i];
        if (t < C) b2s[t] = b2[t];
        if (t < H) b1s[t] = b1[t];
        __syncthreads();
    }
    int lane = t & 63;
    int nib  = (t >> 6) * 8 + (lane >> 3);   // node-in-block 0..31
    int l    = lane & 7;                     // feature octet
    int node = blockIdx.x * 32 + nib;
    bool nv  = node < N;
    int nodec = nv ? node : N - 1;
    int start = row_ptr[nodec];
    int deg   = nv ? (row_ptr[nodec + 1] - start) : 0;
    int md = deg;                            // wave max degree (uniform per octet)
    md = max(md, __shfl_xor(md, 8, 64));
    md = max(md, __shfl_xor(md, 16, 64));
    md = max(md, __shfl_xor(md, 32, 64));
    float s0=0.f,s1=0.f,s2=0.f,s3=0.f,s4=0.f,s5=0.f,s6=0.f,s7=0.f;
    for (int j = 0; j < md; j += 2) {
        bool a0 = j < deg;
        bool a1 = j + 1 < deg;
        int  jc0 = a0 ? start + j : 0;
        int  jc1 = a1 ? start + j + 1 : 0;
        int2 e0 = ep[jc0];
        int2 e1 = ep[jc1];
        float w0 = a0 ? __int_as_float(e0.y) : 0.0f;
        float w1 = a1 ? __int_as_float(e1.y) : 0.0f;
        uint4 v0 = hin[(size_t)e0.x * (H / 8) + l];
        uint4 v1 = hin[(size_t)e1.x * (H / 8) + l];
        s0 = fmaf(w0, bf16_lo(v0.x), s0); s1 = fmaf(w0, bf16_hi(v0.x), s1);
        s2 = fmaf(w0, bf16_lo(v0.y), s2); s3 = fmaf(w0, bf16_hi(v0.y), s3);
        s4 = fmaf(w0, bf16_lo(v0.z), s4); s5 = fmaf(w0, bf16_hi(v0.z), s5);
        s6 = fmaf(w0, bf16_lo(v0.w), s6); s7 = fmaf(w0, bf16_hi(v0.w), s7);
        s0 = fmaf(w1, bf16_lo(v1.x), s0); s1 = fmaf(w1, bf16_hi(v1.x), s1);
        s2 = fmaf(w1, bf16_lo(v1.y), s2); s3 = fmaf(w1, bf16_hi(v1.y), s3);
        s4 = fmaf(w1, bf16_lo(v1.z), s4); s5 = fmaf(w1, bf16_hi(v1.z), s5);
        s6 = fmaf(w1, bf16_lo(v1.w), s6); s7 = fmaf(w1, bf16_hi(v1.w), s7);
    }
    if (nv) {
        size_t base = (size_t)node * (H / 8) + l;
        float d2 = dinv2[node];
        uint4 hv = hin[base];              // self-loop term
        s0 = fmaf(d2, bf16_lo(hv.x), s0); s1 = fmaf(d2, bf16_hi(hv.x), s1);
        s2 = fmaf(d2, bf16_lo(hv.y), s2); s3 = fmaf(d2, bf16_hi(hv.y), s3);
        s4 = fmaf(d2, bf16_lo(hv.z), s4); s5 = fmaf(d2, bf16_hi(hv.z), s5);
        s6 = fmaf(d2, bf16_lo(hv.w), s6); s7 = fmaf(d2, bf16_hi(hv.w), s7);
        if (WRITE_H) {
            uint4 o;
            o.x = (bf16_rne(s1) << 16) | bf16_rne(s0);
            o.y = (bf16_rne(s3) << 16) | bf16_rne(s2);
            o.z = (bf16_rne(s5) << 16) | bf16_rne(s4);
            o.w = (bf16_rne(s7) << 16) | bf16_rne(s6);
            hout[base] = o;
        }
        uint4* ap = (uint4*)(acch + (size_t)node * H + l * 8);
        if (FINAL) {
            uint4 old = *ap;               // acc of hops 0..K-2
            float2 f;
            f = __half22float2(*(__half2*)&old.x); s0 += f.x; s1 += f.y;
            f = __half22float2(*(__half2*)&old.y); s2 += f.x; s3 += f.y;
            f = __half22float2(*(__half2*)&old.z); s4 += f.x; s5 += f.y;
            f = __half22float2(*(__half2*)&old.w); s6 += f.x; s7 += f.y;
            float4 ya = y04[(size_t)node * (H / 4) + 2 * l];
            float4 yb = y04[(size_t)node * (H / 4) + 2 * l + 1];
            const float* bp = b1s + l * 8;
            float* hp = hs + nib * H + l * 8;
            hp[0] = fmaxf(fmaf(CK, s0, fmaf(AL, ya.x, bp[0])), 0.f);
            hp[1] = fmaxf(fmaf(CK, s1, fmaf(AL, ya.y, bp[1])), 0.f);
            hp[2] = fmaxf(fmaf(CK, s2, fmaf(AL, ya.z, bp[2])), 0.f);
            hp[3] = fmaxf(fmaf(CK, s3, fmaf(AL, ya.w, bp[3])), 0.f);
            hp[4] = fmaxf(fmaf(CK, s4, fmaf(AL, yb.x, bp[4])), 0.f);
            hp[5] = fmaxf(fmaf(CK, s5, fmaf(AL, yb.y, bp[5])), 0.f);
            hp[6] = fmaxf(fmaf(CK, s6, fmaf(AL, yb.z, bp[6])), 0.f);
            hp[7] = fmaxf(fmaf(CK, s7, fmaf(AL, yb.w, bp[7])), 0.f);
        } else {
            if (!ACC_INIT) {
                uint4 old = *ap;
                float2 f;
                f = __half22float2(*(__half2*)&old.x); s0 += f.x; s1 += f.y;
                f = __half22float2(*(__half2*)&old.y); s2 += f.x; s3 += f.y;
                f = __half22float2(*(__half2*)&old.z); s4 += f.x; s5 += f.y;
                f = __half22float2(*(__half2*)&old.w); s6 += f.x; s7 += f.y;
            }
            uint4 nvp;
            __half2 h;
            h = __floats2half2_rn(s0, s1); nvp.x = *(unsigned*)&h;
            h = __floats2half2_rn(s2, s3); nvp.y = *(unsigned*)&h;
            h = __floats2half2_rn(s4, s5); nvp.z = *(unsigned*)&h;
            h = __floats2half2_rn(s6, s7); nvp.w = *(unsigned*)&h;
            *ap = nvp;
        }
    }
    if (FINAL) {
        __syncthreads();
        int node0 = blockIdx.x * 32;
        for (int o = t; o < 32 * C; o += 256) {
            int nl = o / C, c = o % C;
            int n2 = node0 + nl;
            if (n2 >= N) continue;
            float s = b2s[c];
            const float* hr = &hs[nl * H];
#pragma unroll
            for (int k = 0; k < H; ++k) s = fmaf(hr[k], w2s[k * C + c], s);
            out[n2 * C + c] = s;
        }
    }
}

// ---------------------------------------------------------------------------
extern "C" void kernel_launch(void* const* d_in, const int* in_sizes, int n_in,
                              void* d_out, int out_size, void* d_ws, size_t ws_size,
                              hipStream_t stream) {
    const float* x  = (const float*)d_in[0];
    const int*   ei = (const int*)d_in[1];
    const float* ew = (const float*)d_in[2];
    const float* W1 = (const float*)d_in[3];
    const float* b1 = (const float*)d_in[4];
    const float* W2 = (const float*)d_in[5];
    const float* b2 = (const float*)d_in[6];
    float* out = (float*)d_out;

    const int* row = ei;        // edge_index[0]
    const int* col = ei + E;    // edge_index[1]

    char* ws = (char*)d_ws;
    size_t off = 0;
    auto alloc = [&](size_t bytes) -> char* {
        char* p = ws + off;
        off = (off + bytes + 1023) & ~(size_t)1023;
        return p;
    };
    float*          y0  = (float*)alloc((size_t)N * H * 4);
    unsigned short* y0b = (unsigned short*)alloc((size_t)N * H * 2);
    unsigned short* ha  = (unsigned short*)alloc((size_t)N * H * 2);
    unsigned short* hb  = (unsigned short*)alloc((size_t)N * H * 2);
    __half*         acch= (__half*)alloc((size_t)N * H * 2);
    int*   cnt8   = (int*)  alloc((size_t)8 * N * 4);  // zeroed
    int*   fill   = (int*)  alloc((size_t)N * 4);      // zeroed
    float* dinv   = (float*)alloc((size_t)N * 4);
    float* dinv2  = (float*)alloc((size_t)N * 4);
    int*   row_ptr= (int*)  alloc((size_t)(N + 1) * 4);
    int*   bsum   = (int*)  alloc(64 * 4);
    int*   boff   = (int*)  alloc(64 * 4);
    int2*  ep     = (int2*) alloc((size_t)E * 8);

    // zero cnt8|fill (contiguous in bump order)
    hipMemsetAsync(cnt8, 0, (size_t)((char*)dinv - (char*)cnt8), stream);

    // 1) y0 = x @ W1 (fp32 out + bf16 out)
    k_gemm1<<<(N + G1N - 1) / G1N, 256, 0, stream>>>(x, W1, y0, y0b);

    // 2) per-row edge counts (privatized)
    k_count<<<(E + 255) / 256, 256, 0, stream>>>(row, cnt8);

    // 3) scan counts -> row_ptr
    constexpr int NB = (N + 1023) / 1024;  // 49
    k_scan_blocks<<<NB, 1024, 0, stream>>>(cnt8, row_ptr, bsum);
    k_scan_sums<<<1, 64, 0, stream>>>(bsum, boff, NB);
    k_addoff<<<NB, 1024, 0, stream>>>(row_ptr, boff);

    // 4) CSR scatter, weighted degree + dinv, normalize in place
    k_scatter<<<(E + 255) / 256, 256, 0, stream>>>(row, col, ew, row_ptr, fill, ep);
    k_deg_dinv<<<(N + 255) / 256, 256, 0, stream>>>(ep, row_ptr, dinv, dinv2);
    k_norm<<<(N + 31) / 32, 256, 0, stream>>>(ep, row_ptr, dinv);

    // 5) K hops; hop 0 inits acc, hop K-1 fuses the MLP epilogue
    const uint4* hin = (const uint4*)y0b;
    uint4* bufs[2] = {(uint4*)ha, (uint4*)hb};
    int grid = (N + 31) / 32;   // 1563 blocks, 32 nodes/block
    for (int hop = 0; hop < K; ++hop) {
        uint4* hout = bufs[hop & 1];
        if (hop == 0)
            k_prop<true, true, false><<<grid, 256, 0, stream>>>(hin, hout, acch, dinv2,
                row_ptr, ep, (const float4*)y0, b1, W2, b2, out);
        else if (hop == K - 1)
            k_prop<false, false, true><<<grid, 256, 0, stream>>>(hin, hout, acch, dinv2,
                row_ptr, ep, (const float4*)y0, b1, W2, b2, out);
        else
            k_prop<true, false, false><<<grid, 256, 0, stream>>>(hin, hout, acch, dinv2,
                row_ptr, ep, (const float4*)y0, b1, W2, b2, out);
        hin = hout;
    }
}